// Round 1
// baseline (458.701 us; speedup 1.0000x reference)
//
#include <hip/hip_runtime.h>
#include <math.h>

// Problem constants (ConvAttention: B=8, C=192, H=W=28, heads=6, ch=32, G=4)
namespace {
constexpr int kB = 8;
constexpr int kC = 192;
constexpr int kH = 28;
constexpr int kW = 28;
constexpr int kN = 784;          // kH * kW
constexpr int kHEADS = 6;
constexpr int kCH = 32;          // kC / kHEADS
constexpr int kG = 4;
constexpr float kEPS = 1e-5f;
constexpr float kSCALE = 0.07216878364870322f;  // 192^-0.5
}

// ---------------------------------------------------------------------------
// K1: depthwise 3x3 conv + BN (eval) for q,k,v branches in one pass.
// x layout (B, N, C) with C fastest -> threads over c are coalesced.
// Outputs QD/KD/VD in (b, n, c) layout (c fastest).
// ---------------------------------------------------------------------------
__global__ __launch_bounds__(192) void dwbn_kernel(
    const float* __restrict__ x,
    const float* __restrict__ wq, const float* __restrict__ gq,
    const float* __restrict__ bq, const float* __restrict__ mq,
    const float* __restrict__ vq,
    const float* __restrict__ wk, const float* __restrict__ gk,
    const float* __restrict__ bk, const float* __restrict__ mk,
    const float* __restrict__ vk,
    const float* __restrict__ wv, const float* __restrict__ gv,
    const float* __restrict__ bv, const float* __restrict__ mv,
    const float* __restrict__ vv,
    float* __restrict__ qd, float* __restrict__ kd, float* __restrict__ vd)
{
    const int c = threadIdx.x;              // 0..191
    const int blk = blockIdx.x;             // 0 .. kB*98-1
    const int b = blk / 98;
    const int p0 = (blk % 98) * 8;

    float wwq[9], wwk[9], wwv[9];
#pragma unroll
    for (int t = 0; t < 9; ++t) {
        wwq[t] = wq[c * 9 + t];
        wwk[t] = wk[c * 9 + t];
        wwv[t] = wv[c * 9 + t];
    }
    const float invq = gq[c] * rsqrtf(vq[c] + kEPS);
    const float addq = bq[c] - mq[c] * invq;
    const float invk = gk[c] * rsqrtf(vk[c] + kEPS);
    const float addk = bk[c] - mk[c] * invk;
    const float invv = gv[c] * rsqrtf(vv[c] + kEPS);
    const float addv = bv[c] - mv[c] * invv;

    const float* xb = x + (size_t)b * kN * kC;

    for (int p = 0; p < 8; ++p) {
        const int n = p0 + p;
        const int i = n / kW;
        const int j = n % kW;
        float aq = 0.f, ak = 0.f, av = 0.f;
#pragma unroll
        for (int di = -1; di <= 1; ++di) {
            const int ii = i + di;
            if (ii < 0 || ii >= kH) continue;
#pragma unroll
            for (int dj = -1; dj <= 1; ++dj) {
                const int jj = j + dj;
                if (jj < 0 || jj >= kW) continue;
                const float xv = xb[(size_t)(ii * kW + jj) * kC + c];
                const int t = (di + 1) * 3 + (dj + 1);
                aq += xv * wwq[t];
                ak += xv * wwk[t];
                av += xv * wwv[t];
            }
        }
        const size_t o = ((size_t)b * kN + n) * kC + c;
        qd[o] = aq * invq + addq;
        kd[o] = ak * invk + addk;
        vd[o] = av * invv + addv;
    }
}

// ---------------------------------------------------------------------------
// K2: 1x1 projections. Out[o,n] = sum_c W[o,c] * X[n,c] + bias[o].
// X in (b, n, c). Q,K written (b, o, n). V written transposed (b, head, n, ch).
// 64x64 output tile, K-step 32, 256 threads, 4x4 accum per thread.
// ---------------------------------------------------------------------------
__global__ __launch_bounds__(256) void proj_kernel(
    const float* __restrict__ qd, const float* __restrict__ kd,
    const float* __restrict__ vd,
    const float* __restrict__ pqw, const float* __restrict__ pqb,
    const float* __restrict__ pkw, const float* __restrict__ pkb,
    const float* __restrict__ pvw, const float* __restrict__ pvb,
    float* __restrict__ Q, float* __restrict__ K, float* __restrict__ VT)
{
    const int br = blockIdx.z % 3;
    const int b  = blockIdx.z / 3;
    const float* X    = (br == 0) ? qd  : (br == 1) ? kd  : vd;
    const float* Wm   = (br == 0) ? pqw : (br == 1) ? pkw : pvw;
    const float* bias = (br == 0) ? pqb : (br == 1) ? pkb : pvb;

    __shared__ float Ws[64][33];   // [o][c], +1 pad breaks bank conflicts
    __shared__ float Xs[32][65];   // [c][n]

    const int o0 = blockIdx.y * 64;
    const int n0 = blockIdx.x * 64;
    const int t  = threadIdx.x;
    const int tx = t % 16, ty = t / 16;

    float acc[4][4] = {};

    for (int c0 = 0; c0 < kC; c0 += 32) {
#pragma unroll
        for (int k = 0; k < 8; ++k) {
            const int idx = t + k * 256;
            const int col = idx & 31, row = idx >> 5;
            Ws[row][col] = Wm[(size_t)(o0 + row) * kC + c0 + col];
        }
#pragma unroll
        for (int k = 0; k < 8; ++k) {
            const int idx = t + k * 256;
            const int cc = idx & 31, nn = idx >> 5;
            const int n = n0 + nn;
            Xs[cc][nn] = (n < kN) ? X[((size_t)b * kN + n) * kC + c0 + cc] : 0.f;
        }
        __syncthreads();
#pragma unroll
        for (int k = 0; k < 32; ++k) {
            float wa[4], xa[4];
#pragma unroll
            for (int a = 0; a < 4; ++a) wa[a] = Ws[ty * 4 + a][k];
#pragma unroll
            for (int e = 0; e < 4; ++e) xa[e] = Xs[k][tx * 4 + e];
#pragma unroll
            for (int a = 0; a < 4; ++a)
#pragma unroll
                for (int e = 0; e < 4; ++e) acc[a][e] += wa[a] * xa[e];
        }
        __syncthreads();
    }

#pragma unroll
    for (int a = 0; a < 4; ++a) {
        const int o = o0 + ty * 4 + a;
        const float bi = bias[o];
#pragma unroll
        for (int e = 0; e < 4; ++e) {
            const int n = n0 + tx * 4 + e;
            if (n >= kN) continue;
            const float val = acc[a][e] + bi;
            if (br == 2) {
                const int hh = o >> 5, cc = o & 31;
                VT[(((size_t)b * kHEADS + hh) * kN + n) * kCH + cc] = val;
            } else {
                float* O = (br == 0) ? Q : K;
                O[((size_t)b * kC + o) * kN + n] = val;
            }
        }
    }
}

// ---------------------------------------------------------------------------
// K3: attention for one (b, head, 16-query tile).
// scores -> LDS (16x784), softmax (16-lane-group shfl reduce, normalize folded
// into PV epilogue), PV from transposed V. Output written in (ch*6+head)
// channel order, layout (b, u, n).
// ---------------------------------------------------------------------------
__global__ __launch_bounds__(256) void attn_kernel(
    const float* __restrict__ Q, const float* __restrict__ K,
    const float* __restrict__ VT, float* __restrict__ AO)
{
    const int blk = blockIdx.x;
    const int it = blk % 49;
    const int hh = (blk / 49) % kHEADS;
    const int b  = blk / (49 * kHEADS);
    const int i0 = it * 16;
    const int t = threadIdx.x;

    __shared__ float qs[16][32];
    __shared__ float ps[16][784];
    __shared__ float ssum[16];

    const float* Qb = Q + ((size_t)b * kC + hh * kCH) * kN;
    const float* Kb = K + ((size_t)b * kC + hh * kCH) * kN;
    const float* Vb = VT + ((size_t)b * kHEADS + hh) * (size_t)kN * kCH;

#pragma unroll
    for (int k = 0; k < 2; ++k) {
        const int idx = t + k * 256;
        const int ii = idx & 15, c = idx >> 4;
        qs[ii][c] = Qb[(size_t)c * kN + i0 + ii];
    }
    __syncthreads();

    // phase 1: scores s[i][j] = scale * sum_c q[i][c] k[c][j]
    for (int j0 = 0; j0 < kN; j0 += 256) {
        const int j = j0 + t;
        if (j < kN) {
            float s[16] = {};
#pragma unroll 8
            for (int c = 0; c < 32; ++c) {
                const float kc = Kb[(size_t)c * kN + j];
#pragma unroll
                for (int ii = 0; ii < 16; ++ii) s[ii] += qs[ii][c] * kc;
            }
#pragma unroll
            for (int ii = 0; ii < 16; ++ii) ps[ii][j] = s[ii] * kSCALE;
        }
    }
    __syncthreads();

    // phase 2: row softmax (unnormalized exp; 1/sum applied in PV epilogue)
    {
        const int r = t >> 4;
        const int l = t & 15;
        float m = -1e30f;
        for (int j = l; j < kN; j += 16) m = fmaxf(m, ps[r][j]);
#pragma unroll
        for (int mk = 8; mk >= 1; mk >>= 1) m = fmaxf(m, __shfl_xor(m, mk, 16));
        float sum = 0.f;
        for (int j = l; j < kN; j += 16) {
            const float e = __expf(ps[r][j] - m);
            ps[r][j] = e;
            sum += e;
        }
#pragma unroll
        for (int mk = 8; mk >= 1; mk >>= 1) sum += __shfl_xor(sum, mk, 16);
        if (l == 0) ssum[r] = sum;
    }
    __syncthreads();

    // phase 3: out[c,i] = (sum_j p[i][j] v[j][c]) / ssum[i]
    {
        const int c = t & 31;
        const int ib = t >> 5;   // 0..7 -> rows ib and ib+8
        float a0 = 0.f, a1 = 0.f;
#pragma unroll 4
        for (int j = 0; j < kN; ++j) {
            const float v = Vb[(size_t)j * kCH + c];
            a0 += ps[ib][j] * v;
            a1 += ps[ib + 8][j] * v;
        }
        float* AOb = AO + (size_t)b * kC * kN;
        AOb[(size_t)(c * kHEADS + hh) * kN + i0 + ib]     = a0 / ssum[ib];
        AOb[(size_t)(c * kHEADS + hh) * kN + i0 + ib + 8] = a1 / ssum[ib + 8];
    }
}

// ---------------------------------------------------------------------------
// K4: output projection y[b,o,g,n] = sum_u po_w[o,u] AO[b,u,n] + po_b[o],
// broadcast over g=0..3. AO in (b, u, n).
// ---------------------------------------------------------------------------
__global__ __launch_bounds__(256) void outproj_kernel(
    const float* __restrict__ AO, const float* __restrict__ powt,
    const float* __restrict__ pob, float* __restrict__ Y)
{
    const int b = blockIdx.z;
    __shared__ float Ws[64][33];
    __shared__ float Xs[32][65];

    const int o0 = blockIdx.y * 64;
    const int n0 = blockIdx.x * 64;
    const int t  = threadIdx.x;
    const int tx = t % 16, ty = t / 16;

    float acc[4][4] = {};

    for (int c0 = 0; c0 < kC; c0 += 32) {
#pragma unroll
        for (int k = 0; k < 8; ++k) {
            const int idx = t + k * 256;
            const int col = idx & 31, row = idx >> 5;
            Ws[row][col] = powt[(size_t)(o0 + row) * kC + c0 + col];
        }
#pragma unroll
        for (int k = 0; k < 8; ++k) {
            const int idx = t + k * 256;
            const int nn = idx & 63, uu = idx >> 6;
            const int n = n0 + nn;
            Xs[uu][nn] = (n < kN) ? AO[((size_t)b * kC + c0 + uu) * kN + n] : 0.f;
        }
        __syncthreads();
#pragma unroll
        for (int k = 0; k < 32; ++k) {
            float wa[4], xa[4];
#pragma unroll
            for (int a = 0; a < 4; ++a) wa[a] = Ws[ty * 4 + a][k];
#pragma unroll
            for (int e = 0; e < 4; ++e) xa[e] = Xs[k][tx * 4 + e];
#pragma unroll
            for (int a = 0; a < 4; ++a)
#pragma unroll
                for (int e = 0; e < 4; ++e) acc[a][e] += wa[a] * xa[e];
        }
        __syncthreads();
    }

#pragma unroll
    for (int a = 0; a < 4; ++a) {
        const int o = o0 + ty * 4 + a;
        const float bi = pob[o];
#pragma unroll
        for (int e = 0; e < 4; ++e) {
            const int n = n0 + tx * 4 + e;
            if (n >= kN) continue;
            const float val = acc[a][e] + bi;
#pragma unroll
            for (int g = 0; g < kG; ++g) {
                Y[(((size_t)b * kC + o) * kG + g) * kN + n] = val;
            }
        }
    }
}

extern "C" void kernel_launch(void* const* d_in, const int* in_sizes, int n_in,
                              void* d_out, int out_size, void* d_ws, size_t ws_size,
                              hipStream_t stream) {
    const float* x     = (const float*)d_in[0];
    // d_in[1]=h, d_in[2]=w (always 28; ignored)
    const float* dwq_w = (const float*)d_in[3];
    const float* bnq_g = (const float*)d_in[4];
    const float* bnq_b = (const float*)d_in[5];
    const float* bnq_m = (const float*)d_in[6];
    const float* bnq_v = (const float*)d_in[7];
    const float* pq_w  = (const float*)d_in[8];
    const float* pq_b  = (const float*)d_in[9];
    const float* dwk_w = (const float*)d_in[10];
    const float* bnk_g = (const float*)d_in[11];
    const float* bnk_b = (const float*)d_in[12];
    const float* bnk_m = (const float*)d_in[13];
    const float* bnk_v = (const float*)d_in[14];
    const float* pk_w  = (const float*)d_in[15];
    const float* pk_b  = (const float*)d_in[16];
    const float* dwv_w = (const float*)d_in[17];
    const float* bnv_g = (const float*)d_in[18];
    const float* bnv_b = (const float*)d_in[19];
    const float* bnv_m = (const float*)d_in[20];
    const float* bnv_v = (const float*)d_in[21];
    const float* pv_w  = (const float*)d_in[22];
    const float* pv_b  = (const float*)d_in[23];
    const float* po_w  = (const float*)d_in[24];
    const float* po_b  = (const float*)d_in[25];

    float* ws = (float*)d_ws;
    const size_t BCN = (size_t)kB * kC * kN;  // 1,204,224 floats per buffer
    float* QD = ws;
    float* KD = ws + BCN;
    float* VD = ws + 2 * BCN;
    float* Qp = ws + 3 * BCN;
    float* Kp = ws + 4 * BCN;
    float* VT = ws + 5 * BCN;
    float* AO = QD;  // QD/KD/VD are dead after proj_kernel; reuse QD's space

    dwbn_kernel<<<dim3(kB * 98), dim3(192), 0, stream>>>(
        x,
        dwq_w, bnq_g, bnq_b, bnq_m, bnq_v,
        dwk_w, bnk_g, bnk_b, bnk_m, bnk_v,
        dwv_w, bnv_g, bnv_b, bnv_m, bnv_v,
        QD, KD, VD);

    proj_kernel<<<dim3(13, 3, kB * 3), dim3(256), 0, stream>>>(
        QD, KD, VD, pq_w, pq_b, pk_w, pk_b, pv_w, pv_b, Qp, Kp, VT);

    attn_kernel<<<dim3(kB * kHEADS * 49), dim3(256), 0, stream>>>(Qp, Kp, VT, AO);

    outproj_kernel<<<dim3(13, 3, kB), dim3(256), 0, stream>>>(
        AO, po_w, po_b, (float*)d_out);
}

// Round 2
// 188.541 us; speedup vs baseline: 2.4329x; 2.4329x over previous
//
#include <hip/hip_runtime.h>
#include <math.h>

// Problem constants (ConvAttention: B=8, C=192, H=W=28, heads=6, ch=32, G=4)
namespace {
constexpr int kB = 8;
constexpr int kC = 192;
constexpr int kH = 28;
constexpr int kW = 28;
constexpr int kN = 784;          // kH * kW
constexpr int kHEADS = 6;
constexpr int kCH = 32;          // kC / kHEADS
constexpr int kG = 4;
constexpr float kEPS = 1e-5f;
constexpr float kSCALE = 0.07216878364870322f;  // 192^-0.5
}

typedef __attribute__((ext_vector_type(8))) short bf16x8;
typedef __attribute__((ext_vector_type(4))) float f32x4;

// f32 -> bf16 bits, round-to-nearest-even
static __device__ __forceinline__ unsigned short f2bf(float f) {
    union { float f; unsigned int u; } v; v.f = f;
    unsigned int r = v.u + 0x7fffu + ((v.u >> 16) & 1u);
    return (unsigned short)(r >> 16);
}

// ---------------------------------------------------------------------------
// K1: depthwise 3x3 conv + BN (eval) for q,k,v branches in one pass.
// x layout (B, N, C) with C fastest -> threads over c are coalesced.
// Outputs QD/KD/VD in (b, n, c) layout (c fastest), f32.
// ---------------------------------------------------------------------------
__global__ __launch_bounds__(192) void dwbn_kernel(
    const float* __restrict__ x,
    const float* __restrict__ wq, const float* __restrict__ gq,
    const float* __restrict__ bq, const float* __restrict__ mq,
    const float* __restrict__ vq,
    const float* __restrict__ wk, const float* __restrict__ gk,
    const float* __restrict__ bk, const float* __restrict__ mk,
    const float* __restrict__ vk,
    const float* __restrict__ wv, const float* __restrict__ gv,
    const float* __restrict__ bv, const float* __restrict__ mv,
    const float* __restrict__ vv,
    float* __restrict__ qd, float* __restrict__ kd, float* __restrict__ vd)
{
    const int c = threadIdx.x;              // 0..191
    const int blk = blockIdx.x;             // 0 .. kB*98-1
    const int b = blk / 98;
    const int p0 = (blk % 98) * 8;

    float wwq[9], wwk[9], wwv[9];
#pragma unroll
    for (int t = 0; t < 9; ++t) {
        wwq[t] = wq[c * 9 + t];
        wwk[t] = wk[c * 9 + t];
        wwv[t] = wv[c * 9 + t];
    }
    const float invq = gq[c] * rsqrtf(vq[c] + kEPS);
    const float addq = bq[c] - mq[c] * invq;
    const float invk = gk[c] * rsqrtf(vk[c] + kEPS);
    const float addk = bk[c] - mk[c] * invk;
    const float invv = gv[c] * rsqrtf(vv[c] + kEPS);
    const float addv = bv[c] - mv[c] * invv;

    const float* xb = x + (size_t)b * kN * kC;

    for (int p = 0; p < 8; ++p) {
        const int n = p0 + p;
        const int i = n / kW;
        const int j = n % kW;
        float aq = 0.f, ak = 0.f, av = 0.f;
#pragma unroll
        for (int di = -1; di <= 1; ++di) {
            const int ii = i + di;
            if (ii < 0 || ii >= kH) continue;
#pragma unroll
            for (int dj = -1; dj <= 1; ++dj) {
                const int jj = j + dj;
                if (jj < 0 || jj >= kW) continue;
                const float xv = xb[(size_t)(ii * kW + jj) * kC + c];
                const int t = (di + 1) * 3 + (dj + 1);
                aq += xv * wwq[t];
                ak += xv * wwk[t];
                av += xv * wwv[t];
            }
        }
        const size_t o = ((size_t)b * kN + n) * kC + c;
        qd[o] = aq * invq + addq;
        kd[o] = ak * invk + addk;
        vd[o] = av * invv + addv;
    }
}

// ---------------------------------------------------------------------------
// K2: 1x1 projections. Out[o,n] = sum_c W[o,c] * X[n,c] + bias[o].
// X in (b, n, c) f32. Outputs:
//   Q, K -> bf16, (b, head, n, ch) layout  (MFMA A/B-fragment friendly)
//           Q additionally pre-scaled by kSCALE.
//   V    -> bf16, (b, o, n) = (b, head, ch, n) layout.
// 64x64 output tile, K-step 32, 256 threads, 4x4 accum per thread.
// ---------------------------------------------------------------------------
__global__ __launch_bounds__(256) void proj_kernel(
    const float* __restrict__ qd, const float* __restrict__ kd,
    const float* __restrict__ vd,
    const float* __restrict__ pqw, const float* __restrict__ pqb,
    const float* __restrict__ pkw, const float* __restrict__ pkb,
    const float* __restrict__ pvw, const float* __restrict__ pvb,
    unsigned short* __restrict__ Qbf, unsigned short* __restrict__ Kbf,
    unsigned short* __restrict__ Vbf)
{
    const int br = blockIdx.z % 3;
    const int b  = blockIdx.z / 3;
    const float* X    = (br == 0) ? qd  : (br == 1) ? kd  : vd;
    const float* Wm   = (br == 0) ? pqw : (br == 1) ? pkw : pvw;
    const float* bias = (br == 0) ? pqb : (br == 1) ? pkb : pvb;

    __shared__ union {
        struct { float Ws[64][33]; float Xs[32][65]; } s;
        float sbuf[64][65];
    } u;

    const int o0 = blockIdx.y * 64;
    const int n0 = blockIdx.x * 64;
    const int t  = threadIdx.x;
    const int tx = t % 16, ty = t / 16;

    float acc[4][4] = {};

    for (int c0 = 0; c0 < kC; c0 += 32) {
#pragma unroll
        for (int k = 0; k < 8; ++k) {
            const int idx = t + k * 256;
            const int col = idx & 31, row = idx >> 5;
            u.s.Ws[row][col] = Wm[(size_t)(o0 + row) * kC + c0 + col];
        }
#pragma unroll
        for (int k = 0; k < 8; ++k) {
            const int idx = t + k * 256;
            const int cc = idx & 31, nn = idx >> 5;
            const int n = n0 + nn;
            u.s.Xs[cc][nn] = (n < kN) ? X[((size_t)b * kN + n) * kC + c0 + cc] : 0.f;
        }
        __syncthreads();
#pragma unroll
        for (int k = 0; k < 32; ++k) {
            float wa[4], xa[4];
#pragma unroll
            for (int a = 0; a < 4; ++a) wa[a] = u.s.Ws[ty * 4 + a][k];
#pragma unroll
            for (int e = 0; e < 4; ++e) xa[e] = u.s.Xs[k][tx * 4 + e];
#pragma unroll
            for (int a = 0; a < 4; ++a)
#pragma unroll
                for (int e = 0; e < 4; ++e) acc[a][e] += wa[a] * xa[e];
        }
        __syncthreads();
    }

    if (br == 2) {
        // V: (b, o, n) bf16, coalesced short4-ish writes (4 consecutive n)
#pragma unroll
        for (int a = 0; a < 4; ++a) {
            const int o = o0 + ty * 4 + a;
            const float bi = bias[o];
            const int n = n0 + tx * 4;
            if (n + 3 < kN) {
                ushort4 pk;
                pk.x = f2bf(acc[a][0] + bi);
                pk.y = f2bf(acc[a][1] + bi);
                pk.z = f2bf(acc[a][2] + bi);
                pk.w = f2bf(acc[a][3] + bi);
                *(ushort4*)&Vbf[((size_t)b * kC + o) * kN + n] = pk;
            }
        }
    } else {
        // Q/K: stage f32 tile in LDS, then write transposed (b,h,n,ch) bf16
        const float sc = (br == 0) ? kSCALE : 1.0f;
#pragma unroll
        for (int a = 0; a < 4; ++a) {
            const int o = o0 + ty * 4 + a;
            const float bi = bias[o];
#pragma unroll
            for (int e = 0; e < 4; ++e)
                u.sbuf[ty * 4 + a][tx * 4 + e] = (acc[a][e] + bi) * sc;
        }
        __syncthreads();
        unsigned short* Obf = (br == 0) ? Qbf : Kbf;
#pragma unroll
        for (int rep = 0; rep < 16; ++rep) {
            const int idx = t + rep * 256;
            const int ol = idx & 63, nl = idx >> 6;
            const int n = n0 + nl;
            if (n < kN) {
                const int o = o0 + ol;
                Obf[(((size_t)b * kHEADS + (o >> 5)) * kN + n) * kCH + (o & 31)] =
                    f2bf(u.sbuf[ol][nl]);
            }
        }
    }
}

// ---------------------------------------------------------------------------
// K3: attention for one (b, head, 16-query tile), MFMA bf16.
// Phase 1: S(16x784) = Q(16x32) * K^T via mfma_f32_16x16x32_bf16 (49 tiles).
// Phase 2: f32 softmax in LDS (scale pre-folded into Q), stores 1/sum.
// Phase 3: O(16x32) = P(16x800, zero-padded) * V via 25 K-steps, split over
//          4 waves (2 col-tiles x 2 k-halves), cross-wave reduce in LDS.
// Output AO f32 (b, u=c*6+h, n).
// ---------------------------------------------------------------------------
__global__ __launch_bounds__(256) void attn_kernel(
    const unsigned short* __restrict__ Qbf, const unsigned short* __restrict__ Kbf,
    const unsigned short* __restrict__ Vbf, float* __restrict__ AO)
{
    constexpr int PSTR = 812;   // row stride: 812 mod 32 = 12 -> <=2-way banks
    __shared__ float ps[16][PSTR];
    __shared__ float outs[16][32];
    __shared__ float rsum[16];

    const int blk = blockIdx.x;
    const int it = blk % 49;
    const int hh = (blk / 49) % kHEADS;
    const int b  = blk / (49 * kHEADS);
    const int i0 = it * 16;
    const int t = threadIdx.x;
    const int w  = t >> 6;      // wave 0..3
    const int l  = t & 63;
    const int lr = l & 15;      // fragment row/col lane index
    const int lk = l >> 4;      // k-block 0..3

    const unsigned short* Qb = Qbf + (size_t)(b * kHEADS + hh) * kN * kCH;
    const unsigned short* Kb = Kbf + (size_t)(b * kHEADS + hh) * kN * kCH;
    const unsigned short* Vb = Vbf + ((size_t)b * kC + hh * kCH) * kN;

    // Q A-fragment: lane holds Q[i0+lr][lk*8 .. +7] (scale pre-folded)
    const bf16x8 qa = *(const bf16x8*)(Qb + (size_t)(i0 + lr) * kCH + lk * 8);

    // ---- phase 1: scores
    for (int tile = w; tile < 49; tile += 4) {
        const int j0 = tile * 16;
        const bf16x8 kb = *(const bf16x8*)(Kb + (size_t)(j0 + lr) * kCH + lk * 8);
        f32x4 d = {0.f, 0.f, 0.f, 0.f};
        d = __builtin_amdgcn_mfma_f32_16x16x32_bf16(qa, kb, d, 0, 0, 0);
#pragma unroll
        for (int r = 0; r < 4; ++r) ps[lk * 4 + r][j0 + lr] = d[r];
    }
    // zero-pad P columns 784..799 (for the K=32-granular PV loop)
    ps[t >> 4][784 + (t & 15)] = 0.f;
    __syncthreads();

    // ---- phase 2: softmax rows (16 lanes per row), unnormalized exp
    {
        const int r  = t >> 4;
        const int ll = t & 15;
        float m = -1e30f;
        for (int j = ll; j < kN; j += 16) m = fmaxf(m, ps[r][j]);
#pragma unroll
        for (int mk = 8; mk >= 1; mk >>= 1) m = fmaxf(m, __shfl_xor(m, mk, 16));
        float sum = 0.f;
        for (int j = ll; j < kN; j += 16) {
            const float e = __expf(ps[r][j] - m);
            ps[r][j] = e;
            sum += e;
        }
#pragma unroll
        for (int mk = 8; mk >= 1; mk >>= 1) sum += __shfl_xor(sum, mk, 16);
        if (ll == 0) rsum[r] = 1.0f / sum;
    }
    __syncthreads();

    // ---- phase 3: O = P * V  (wave -> col-tile ct, k-half kh)
    const int ct = w & 1;
    const int kh = w >> 1;
    const int c0 = ct * 16;
    f32x4 oa = {0.f, 0.f, 0.f, 0.f};
    const int s_begin = kh ? 12 : 0;
    const int s_end   = kh ? 25 : 12;
    for (int s = s_begin; s < s_end; ++s) {
        const int kk = s * 32;
        // A-frag: P[lr][kk + lk*8 .. +7] f32 -> bf16
        const f32x4 p0 = *(const f32x4*)&ps[lr][kk + lk * 8];
        const f32x4 p1 = *(const f32x4*)&ps[lr][kk + lk * 8 + 4];
        bf16x8 pa;
        pa[0] = (short)f2bf(p0[0]); pa[1] = (short)f2bf(p0[1]);
        pa[2] = (short)f2bf(p0[2]); pa[3] = (short)f2bf(p0[3]);
        pa[4] = (short)f2bf(p1[0]); pa[5] = (short)f2bf(p1[1]);
        pa[6] = (short)f2bf(p1[2]); pa[7] = (short)f2bf(p1[3]);
        // B-frag: V[kk + lk*8 .. +7][c0+lr] from (ch-major) Vbf rows
        const int kbase = kk + lk * 8;
        bf16x8 vbf = {0, 0, 0, 0, 0, 0, 0, 0};
        if (kbase < kN)
            vbf = *(const bf16x8*)(Vb + (size_t)(c0 + lr) * kN + kbase);
        oa = __builtin_amdgcn_mfma_f32_16x16x32_bf16(pa, vbf, oa, 0, 0, 0);
    }
    __syncthreads();
    if (w >= 2) {
#pragma unroll
        for (int r = 0; r < 4; ++r) outs[lk * 4 + r][c0 + lr] = oa[r];
    }
    __syncthreads();
    if (w < 2) {
#pragma unroll
        for (int r = 0; r < 4; ++r) {
            const int row = lk * 4 + r;
            outs[row][c0 + lr] = (outs[row][c0 + lr] + oa[r]) * rsum[row];
        }
    }
    __syncthreads();
    // coalesced-ish AO write: thread t -> channel c = t>>3, 2 consecutive n
    {
        const int c  = t >> 3;
        const int nn = (t & 7) * 2;
        float2 v;
        v.x = outs[nn][c];
        v.y = outs[nn + 1][c];
        *(float2*)&AO[(size_t)b * kC * kN + (size_t)(c * kHEADS + hh) * kN + i0 + nn] = v;
    }
}

// ---------------------------------------------------------------------------
// K4: output projection y[b,o,g,n] = sum_u po_w[o,u] AO[b,u,n] + po_b[o],
// broadcast over g=0..3. AO in (b, u, n).
// ---------------------------------------------------------------------------
__global__ __launch_bounds__(256) void outproj_kernel(
    const float* __restrict__ AO, const float* __restrict__ powt,
    const float* __restrict__ pob, float* __restrict__ Y)
{
    const int b = blockIdx.z;
    __shared__ float Ws[64][33];
    __shared__ float Xs[32][65];

    const int o0 = blockIdx.y * 64;
    const int n0 = blockIdx.x * 64;
    const int t  = threadIdx.x;
    const int tx = t % 16, ty = t / 16;

    float acc[4][4] = {};

    for (int c0 = 0; c0 < kC; c0 += 32) {
#pragma unroll
        for (int k = 0; k < 8; ++k) {
            const int idx = t + k * 256;
            const int col = idx & 31, row = idx >> 5;
            Ws[row][col] = powt[(size_t)(o0 + row) * kC + c0 + col];
        }
#pragma unroll
        for (int k = 0; k < 8; ++k) {
            const int idx = t + k * 256;
            const int nn = idx & 63, uu = idx >> 6;
            const int n = n0 + nn;
            Xs[uu][nn] = (n < kN) ? AO[((size_t)b * kC + c0 + uu) * kN + n] : 0.f;
        }
        __syncthreads();
#pragma unroll
        for (int k = 0; k < 32; ++k) {
            float wa[4], xa[4];
#pragma unroll
            for (int a = 0; a < 4; ++a) wa[a] = Ws[ty * 4 + a][k];
#pragma unroll
            for (int e = 0; e < 4; ++e) xa[e] = Xs[k][tx * 4 + e];
#pragma unroll
            for (int a = 0; a < 4; ++a)
#pragma unroll
                for (int e = 0; e < 4; ++e) acc[a][e] += wa[a] * xa[e];
        }
        __syncthreads();
    }

#pragma unroll
    for (int a = 0; a < 4; ++a) {
        const int o = o0 + ty * 4 + a;
        const float bi = pob[o];
#pragma unroll
        for (int e = 0; e < 4; ++e) {
            const int n = n0 + tx * 4 + e;
            if (n >= kN) continue;
            const float val = acc[a][e] + bi;
#pragma unroll
            for (int g = 0; g < kG; ++g) {
                Y[(((size_t)b * kC + o) * kG + g) * kN + n] = val;
            }
        }
    }
}

extern "C" void kernel_launch(void* const* d_in, const int* in_sizes, int n_in,
                              void* d_out, int out_size, void* d_ws, size_t ws_size,
                              hipStream_t stream) {
    const float* x     = (const float*)d_in[0];
    // d_in[1]=h, d_in[2]=w (always 28; ignored)
    const float* dwq_w = (const float*)d_in[3];
    const float* bnq_g = (const float*)d_in[4];
    const float* bnq_b = (const float*)d_in[5];
    const float* bnq_m = (const float*)d_in[6];
    const float* bnq_v = (const float*)d_in[7];
    const float* pq_w  = (const float*)d_in[8];
    const float* pq_b  = (const float*)d_in[9];
    const float* dwk_w = (const float*)d_in[10];
    const float* bnk_g = (const float*)d_in[11];
    const float* bnk_b = (const float*)d_in[12];
    const float* bnk_m = (const float*)d_in[13];
    const float* bnk_v = (const float*)d_in[14];
    const float* pk_w  = (const float*)d_in[15];
    const float* pk_b  = (const float*)d_in[16];
    const float* dwv_w = (const float*)d_in[17];
    const float* bnv_g = (const float*)d_in[18];
    const float* bnv_b = (const float*)d_in[19];
    const float* bnv_m = (const float*)d_in[20];
    const float* bnv_v = (const float*)d_in[21];
    const float* pv_w  = (const float*)d_in[22];
    const float* pv_b  = (const float*)d_in[23];
    const float* po_w  = (const float*)d_in[24];
    const float* po_b  = (const float*)d_in[25];

    float* ws = (float*)d_ws;
    const size_t BCN = (size_t)kB * kC * kN;  // 1,204,224 elements
    float* QD = ws;
    float* KD = ws + BCN;
    float* VD = ws + 2 * BCN;
    unsigned short* Qbf = (unsigned short*)(ws + 3 * BCN);
    unsigned short* Kbf = Qbf + BCN;
    unsigned short* Vbf = Kbf + BCN;
    float* AO = QD;  // QD/KD/VD dead after proj_kernel; reuse

    dwbn_kernel<<<dim3(kB * 98), dim3(192), 0, stream>>>(
        x,
        dwq_w, bnq_g, bnq_b, bnq_m, bnq_v,
        dwk_w, bnk_g, bnk_b, bnk_m, bnk_v,
        dwv_w, bnv_g, bnv_b, bnv_m, bnv_v,
        QD, KD, VD);

    proj_kernel<<<dim3(13, 3, kB * 3), dim3(256), 0, stream>>>(
        QD, KD, VD, pq_w, pq_b, pk_w, pk_b, pv_w, pv_b, Qbf, Kbf, Vbf);

    attn_kernel<<<dim3(kB * kHEADS * 49), dim3(256), 0, stream>>>(Qbf, Kbf, Vbf, AO);

    outproj_kernel<<<dim3(13, 3, kB), dim3(256), 0, stream>>>(
        AO, po_w, po_b, (float*)d_out);
}

// Round 3
// 86.148 us; speedup vs baseline: 5.3246x; 2.1886x over previous
//
#include <hip/hip_runtime.h>
#include <math.h>

// Problem constants (ConvAttention: B=8, C=192, H=W=28, heads=6, ch=32, G=4)
namespace {
constexpr int kB = 8;
constexpr int kC = 192;
constexpr int kH = 28;
constexpr int kW = 28;
constexpr int kN = 784;          // kH * kW
constexpr int kHEADS = 6;
constexpr int kG = 4;
constexpr float kEPS = 1e-5f;
constexpr float kSCALE = 0.07216878364870322f;  // 192^-0.5
constexpr int kNP = 800;         // padded key rows (25 tiles of 32)
constexpr int kXP = 832;         // padded n rows for X / AO (13 tiles of 64)
}

typedef __attribute__((ext_vector_type(8))) short bf16x8;
typedef __attribute__((ext_vector_type(4))) float f32x4;

// f32 -> bf16 bits, round-to-nearest-even
static __device__ __forceinline__ unsigned short f2bf(float f) {
    union { float f; unsigned int u; } v; v.f = f;
    unsigned int r = v.u + 0x7fffu + ((v.u >> 16) & 1u);
    return (unsigned short)(r >> 16);
}

// ---------------------------------------------------------------------------
// K0: weight prep. Wq/Wk/Wv: f32->bf16 straight copy. Wo: bf16 with column
// permutation Wo'[o][h*32+c] = po_w[o][c*6+h]  (absorbs the (ch,heads)
// channel interleave of the attention output).
// ---------------------------------------------------------------------------
__global__ __launch_bounds__(256) void prep_kernel(
    const float* __restrict__ pqw, const float* __restrict__ pkw,
    const float* __restrict__ pvw, const float* __restrict__ pow_,
    unsigned short* __restrict__ Wq, unsigned short* __restrict__ Wk,
    unsigned short* __restrict__ Wv, unsigned short* __restrict__ Wo)
{
    const int idx = blockIdx.x * 256 + threadIdx.x;
    if (idx >= 4 * kC * kC) return;
    const int mat = idx / (kC * kC);
    const int r = idx % (kC * kC);
    if (mat == 0)      Wq[r] = f2bf(pqw[r]);
    else if (mat == 1) Wk[r] = f2bf(pkw[r]);
    else if (mat == 2) Wv[r] = f2bf(pvw[r]);
    else {
        const int o = r / kC, c = r % kC;
        const int h = c >> 5, ch = c & 31;
        Wo[o * kC + c] = f2bf(pow_[o * kC + ch * kHEADS + h]);
    }
}

// ---------------------------------------------------------------------------
// K1: depthwise 3x3 conv + BN (eval) for q,k,v branches in one pass.
// x (B,N,C) f32, C fastest. Outputs Xq/Xk/Xv bf16 in (b, n[kXP pad], c).
// ---------------------------------------------------------------------------
__global__ __launch_bounds__(192) void dwbn_kernel(
    const float* __restrict__ x,
    const float* __restrict__ wq, const float* __restrict__ gq,
    const float* __restrict__ bq, const float* __restrict__ mq,
    const float* __restrict__ vq,
    const float* __restrict__ wk, const float* __restrict__ gk,
    const float* __restrict__ bk, const float* __restrict__ mk,
    const float* __restrict__ vk,
    const float* __restrict__ wv, const float* __restrict__ gv,
    const float* __restrict__ bv, const float* __restrict__ mv,
    const float* __restrict__ vv,
    unsigned short* __restrict__ xq, unsigned short* __restrict__ xk,
    unsigned short* __restrict__ xv)
{
    const int c = threadIdx.x;              // 0..191
    const int blk = blockIdx.x;             // 0 .. kB*98-1
    const int b = blk / 98;
    const int p0 = (blk % 98) * 8;

    float wwq[9], wwk[9], wwv[9];
#pragma unroll
    for (int t = 0; t < 9; ++t) {
        wwq[t] = wq[c * 9 + t];
        wwk[t] = wk[c * 9 + t];
        wwv[t] = wv[c * 9 + t];
    }
    const float invq = gq[c] * rsqrtf(vq[c] + kEPS);
    const float addq = bq[c] - mq[c] * invq;
    const float invk = gk[c] * rsqrtf(vk[c] + kEPS);
    const float addk = bk[c] - mk[c] * invk;
    const float invv = gv[c] * rsqrtf(vv[c] + kEPS);
    const float addv = bv[c] - mv[c] * invv;

    const float* xb = x + (size_t)b * kN * kC;

    for (int p = 0; p < 8; ++p) {
        const int n = p0 + p;
        const int i = n / kW;
        const int j = n % kW;
        float aq = 0.f, ak = 0.f, av = 0.f;
#pragma unroll
        for (int di = -1; di <= 1; ++di) {
            const int ii = i + di;
            if (ii < 0 || ii >= kH) continue;
#pragma unroll
            for (int dj = -1; dj <= 1; ++dj) {
                const int jj = j + dj;
                if (jj < 0 || jj >= kW) continue;
                const float xvl = xb[(size_t)(ii * kW + jj) * kC + c];
                const int t = (di + 1) * 3 + (dj + 1);
                aq += xvl * wwq[t];
                ak += xvl * wwk[t];
                av += xvl * wwv[t];
            }
        }
        const size_t o = ((size_t)b * kXP + n) * kC + c;
        xq[o] = f2bf(aq * invq + addq);
        xk[o] = f2bf(ak * invk + addk);
        xv[o] = f2bf(av * invv + addv);
    }
}

// ---------------------------------------------------------------------------
// K2: 1x1 projections via MFMA, no LDS. Out[o,n] = sum_c W[o,c] X[n,c] + b[o].
// Block: 64o x 64n tile, 4 waves each 32x32 (2x2 MFMA tiles), 6 k-steps.
// Q,K -> bf16 (b,h, n[kNP], ch) with Q pre-scaled by kSCALE.
// V   -> bf16 (b,h, ch, n[kNP]).
// Rows n in [784,800) get acc(=0-ish)+bias values: harmless, masked in attn.
// ---------------------------------------------------------------------------
__global__ __launch_bounds__(256) void proj_kernel(
    const unsigned short* __restrict__ Xq, const unsigned short* __restrict__ Xk,
    const unsigned short* __restrict__ Xv,
    const unsigned short* __restrict__ Wq, const unsigned short* __restrict__ Wk,
    const unsigned short* __restrict__ Wv,
    const float* __restrict__ bq, const float* __restrict__ bk,
    const float* __restrict__ bv,
    unsigned short* __restrict__ Qb, unsigned short* __restrict__ Kb,
    unsigned short* __restrict__ Vb)
{
    const int br = blockIdx.z % 3;
    const int b  = blockIdx.z / 3;
    const unsigned short* X = (br == 0) ? Xq : (br == 1) ? Xk : Xv;
    const unsigned short* W = (br == 0) ? Wq : (br == 1) ? Wk : Wv;
    const float* bias       = (br == 0) ? bq : (br == 1) ? bk : bv;

    const int n0 = blockIdx.x * 64, o0 = blockIdx.y * 64;
    const int t = threadIdx.x, l = t & 63, w = t >> 6;
    const int q16 = l & 15, u = l >> 4;
    const int ob = o0 + (w >> 1) * 32;
    const int nb = n0 + (w & 1) * 32;

    f32x4 a00 = {0,0,0,0}, a01 = {0,0,0,0}, a10 = {0,0,0,0}, a11 = {0,0,0,0};
    const unsigned short* Wr0 = W + (size_t)(ob + q16) * kC + u * 8;
    const unsigned short* Wr1 = W + (size_t)(ob + 16 + q16) * kC + u * 8;
    const unsigned short* Xr0 = X + ((size_t)b * kXP + nb + q16) * kC + u * 8;
    const unsigned short* Xr1 = X + ((size_t)b * kXP + nb + 16 + q16) * kC + u * 8;
#pragma unroll
    for (int kk = 0; kk < 6; ++kk) {
        const bf16x8 wa0 = *(const bf16x8*)(Wr0 + kk * 32);
        const bf16x8 wa1 = *(const bf16x8*)(Wr1 + kk * 32);
        const bf16x8 xa0 = *(const bf16x8*)(Xr0 + kk * 32);
        const bf16x8 xa1 = *(const bf16x8*)(Xr1 + kk * 32);
        a00 = __builtin_amdgcn_mfma_f32_16x16x32_bf16(wa0, xa0, a00, 0, 0, 0);
        a01 = __builtin_amdgcn_mfma_f32_16x16x32_bf16(wa0, xa1, a01, 0, 0, 0);
        a10 = __builtin_amdgcn_mfma_f32_16x16x32_bf16(wa1, xa0, a10, 0, 0, 0);
        a11 = __builtin_amdgcn_mfma_f32_16x16x32_bf16(wa1, xa1, a11, 0, 0, 0);
    }

    const float sc = (br == 0) ? kSCALE : 1.0f;
#pragma unroll
    for (int ot = 0; ot < 2; ++ot) {
        const int obase = ob + ot * 16;
        const int hh = obase >> 5;
        const int ch0 = (obase & 31) + 4 * u;
        float bi0 = bias[obase + 4 * u + 0], bi1 = bias[obase + 4 * u + 1];
        float bi2 = bias[obase + 4 * u + 2], bi3 = bias[obase + 4 * u + 3];
#pragma unroll
        for (int nt = 0; nt < 2; ++nt) {
            const f32x4 A = (ot == 0) ? (nt == 0 ? a00 : a01)
                                      : (nt == 0 ? a10 : a11);
            const int n = nb + nt * 16 + q16;
            if (n >= kNP) continue;
            if (br < 2) {
                ushort4 p;
                p.x = f2bf((A[0] + bi0) * sc);
                p.y = f2bf((A[1] + bi1) * sc);
                p.z = f2bf((A[2] + bi2) * sc);
                p.w = f2bf((A[3] + bi3) * sc);
                unsigned short* dst = ((br == 0) ? Qb : Kb) +
                    ((size_t)(b * kHEADS + hh) * kNP + n) * 32 + ch0;
                *(ushort4*)dst = p;
            } else {
                unsigned short* dst = Vb +
                    ((size_t)(b * kHEADS + hh) * 32 + ch0) * kNP + n;
                dst[0 * kNP] = f2bf(A[0] + bi0);
                dst[1 * kNP] = f2bf(A[1] + bi1);
                dst[2 * kNP] = f2bf(A[2] + bi2);
                dst[3 * kNP] = f2bf(A[3] + bi3);
            }
        }
    }
}

// ---------------------------------------------------------------------------
// K3: attention. ONE WAVE per (b, head, 16-query tile): no LDS, no barriers.
// Swapped QK^T: d = mfma(A=K_subtile, B=Q) -> lane(q=l&15, u=l>>4) holds
// S[key=base+4u+r][q]. Online softmax in-register; P packed to bf16 in the
// lane-natural key order; V B-fragment loaded in the SAME key order, so
// O += P*V needs no cross-lane shuffle. AO written bf16 (b, n[kXP], h*32+c).
// ---------------------------------------------------------------------------
__global__ __launch_bounds__(256) void attn_kernel(
    const unsigned short* __restrict__ Qbf, const unsigned short* __restrict__ Kbf,
    const unsigned short* __restrict__ Vbf, unsigned short* __restrict__ AO)
{
    const int wid = blockIdx.x * 4 + (threadIdx.x >> 6);
    const int l = threadIdx.x & 63;
    const int qt = wid % 49;
    const int h  = (wid / 49) % kHEADS;
    const int b  = wid / (49 * kHEADS);
    const int i0 = qt * 16;
    const int q16 = l & 15;
    const int u = l >> 4;

    const unsigned short* Qp = Qbf + ((size_t)(b * kHEADS + h) * kNP + i0) * 32;
    const unsigned short* Kp = Kbf + (size_t)(b * kHEADS + h) * kNP * 32;
    const unsigned short* Vr0 = Vbf + ((size_t)(b * kHEADS + h) * 32 + q16) * kNP;
    const unsigned short* Vr1 = Vr0 + (size_t)16 * kNP;

    const bf16x8 qa = *(const bf16x8*)(Qp + q16 * 32 + u * 8);

    f32x4 oa0 = {0.f, 0.f, 0.f, 0.f};
    f32x4 oa1 = {0.f, 0.f, 0.f, 0.f};
    float m = -1e30f, lsum = 0.f;

    for (int tile = 0; tile < 25; ++tile) {
        const int t0 = tile * 32;
        const bf16x8 ka0 = *(const bf16x8*)(Kp + (size_t)(t0 + q16) * 32 + u * 8);
        const bf16x8 ka1 = *(const bf16x8*)(Kp + (size_t)(t0 + 16 + q16) * 32 + u * 8);
        f32x4 d0 = {0.f, 0.f, 0.f, 0.f};
        f32x4 d1 = {0.f, 0.f, 0.f, 0.f};
        d0 = __builtin_amdgcn_mfma_f32_16x16x32_bf16(ka0, qa, d0, 0, 0, 0);
        d1 = __builtin_amdgcn_mfma_f32_16x16x32_bf16(ka1, qa, d1, 0, 0, 0);
        if (t0 + 16 >= kN) {  // last tile: keys t0+16.. are padding -> mask
            d1[0] = -1e30f; d1[1] = -1e30f; d1[2] = -1e30f; d1[3] = -1e30f;
        }
        // tile max for this query (reduce over the 4 u-lanes of query q16)
        float tm = fmaxf(fmaxf(fmaxf(d0[0], d0[1]), fmaxf(d0[2], d0[3])),
                         fmaxf(fmaxf(d1[0], d1[1]), fmaxf(d1[2], d1[3])));
        tm = fmaxf(tm, __shfl_xor(tm, 16));
        tm = fmaxf(tm, __shfl_xor(tm, 32));
        const float newm = fmaxf(m, tm);
        const float alpha = __expf(m - newm);
        const float e0 = __expf(d0[0] - newm), e1 = __expf(d0[1] - newm);
        const float e2 = __expf(d0[2] - newm), e3 = __expf(d0[3] - newm);
        const float e4 = __expf(d1[0] - newm), e5 = __expf(d1[1] - newm);
        const float e6 = __expf(d1[2] - newm), e7 = __expf(d1[3] - newm);
        lsum = lsum * alpha + (((e0 + e1) + (e2 + e3)) + ((e4 + e5) + (e6 + e7)));
        m = newm;
        // O-rescale: alpha per query; O rows of this lane are queries 4u+r
        const float al0 = __shfl(alpha, u * 4 + 0);
        const float al1 = __shfl(alpha, u * 4 + 1);
        const float al2 = __shfl(alpha, u * 4 + 2);
        const float al3 = __shfl(alpha, u * 4 + 3);
        oa0[0] *= al0; oa0[1] *= al1; oa0[2] *= al2; oa0[3] *= al3;
        oa1[0] *= al0; oa1[1] *= al1; oa1[2] *= al2; oa1[3] *= al3;
        // pack P (lane-natural key order: 4u..4u+3, 16+4u..16+4u+3)
        union { unsigned int w[4]; bf16x8 v; } pa;
        pa.w[0] = ((unsigned)f2bf(e1) << 16) | f2bf(e0);
        pa.w[1] = ((unsigned)f2bf(e3) << 16) | f2bf(e2);
        pa.w[2] = ((unsigned)f2bf(e5) << 16) | f2bf(e4);
        pa.w[3] = ((unsigned)f2bf(e7) << 16) | f2bf(e6);
        // V B-fragments in the matching key order
        union { ushort4 hlf[2]; bf16x8 v; } v0, v1;
        v0.hlf[0] = *(const ushort4*)(Vr0 + t0 + 4 * u);
        v0.hlf[1] = *(const ushort4*)(Vr0 + t0 + 16 + 4 * u);
        v1.hlf[0] = *(const ushort4*)(Vr1 + t0 + 4 * u);
        v1.hlf[1] = *(const ushort4*)(Vr1 + t0 + 16 + 4 * u);
        oa0 = __builtin_amdgcn_mfma_f32_16x16x32_bf16(pa.v, v0.v, oa0, 0, 0, 0);
        oa1 = __builtin_amdgcn_mfma_f32_16x16x32_bf16(pa.v, v1.v, oa1, 0, 0, 0);
    }
    // full row sums and reciprocal
    lsum += __shfl_xor(lsum, 16);
    lsum += __shfl_xor(lsum, 32);
    const float rinv = 1.0f / lsum;
    const float r0 = __shfl(rinv, u * 4 + 0);
    const float r1 = __shfl(rinv, u * 4 + 1);
    const float r2 = __shfl(rinv, u * 4 + 2);
    const float r3 = __shfl(rinv, u * 4 + 3);
    // write AO[b][i0+4u+r][h*32 + {q16, 16+q16}]
    unsigned short* aw = AO + ((size_t)b * kXP + i0 + 4 * u) * kC + h * 32 + q16;
    aw[0 * kC + 0]  = f2bf(oa0[0] * r0);
    aw[1 * kC + 0]  = f2bf(oa0[1] * r1);
    aw[2 * kC + 0]  = f2bf(oa0[2] * r2);
    aw[3 * kC + 0]  = f2bf(oa0[3] * r3);
    aw[0 * kC + 16] = f2bf(oa1[0] * r0);
    aw[1 * kC + 16] = f2bf(oa1[1] * r1);
    aw[2 * kC + 16] = f2bf(oa1[2] * r2);
    aw[3 * kC + 16] = f2bf(oa1[3] * r3);
}

// ---------------------------------------------------------------------------
// K4: output projection. Y[o][n] = sum_u Wo'[o][u] AO[n][u] + pob[o],
// broadcast to g=0..3. Block 64o x 64n, wave = one 16-o tile x 64 n.
// ---------------------------------------------------------------------------
__global__ __launch_bounds__(256) void outproj_kernel(
    const unsigned short* __restrict__ AO, const unsigned short* __restrict__ Wo,
    const float* __restrict__ pob, float* __restrict__ Y)
{
    const int b = blockIdx.z;
    const int n0 = blockIdx.x * 64, o0 = blockIdx.y * 64;
    const int t = threadIdx.x, l = t & 63, w = t >> 6;
    const int q16 = l & 15, u = l >> 4;
    const int ob = o0 + w * 16;

    f32x4 c0 = {0,0,0,0}, c1 = {0,0,0,0}, c2 = {0,0,0,0}, c3 = {0,0,0,0};
    const unsigned short* Wr = Wo + (size_t)(ob + q16) * kC + u * 8;
    const unsigned short* Ar = AO + ((size_t)b * kXP + n0 + q16) * kC + u * 8;
#pragma unroll
    for (int kk = 0; kk < 6; ++kk) {
        const bf16x8 a = *(const bf16x8*)(Wr + kk * 32);
        const bf16x8 x0 = *(const bf16x8*)(Ar + (size_t)0 * 16 * kC + kk * 32);
        const bf16x8 x1 = *(const bf16x8*)(Ar + (size_t)1 * 16 * kC + kk * 32);
        const bf16x8 x2 = *(const bf16x8*)(Ar + (size_t)2 * 16 * kC + kk * 32);
        const bf16x8 x3 = *(const bf16x8*)(Ar + (size_t)3 * 16 * kC + kk * 32);
        c0 = __builtin_amdgcn_mfma_f32_16x16x32_bf16(a, x0, c0, 0, 0, 0);
        c1 = __builtin_amdgcn_mfma_f32_16x16x32_bf16(a, x1, c1, 0, 0, 0);
        c2 = __builtin_amdgcn_mfma_f32_16x16x32_bf16(a, x2, c2, 0, 0, 0);
        c3 = __builtin_amdgcn_mfma_f32_16x16x32_bf16(a, x3, c3, 0, 0, 0);
    }
    const float bi0 = pob[ob + 4 * u + 0];
    const float bi1 = pob[ob + 4 * u + 1];
    const float bi2 = pob[ob + 4 * u + 2];
    const float bi3 = pob[ob + 4 * u + 3];
#pragma unroll
    for (int nt = 0; nt < 4; ++nt) {
        const f32x4 A = (nt == 0) ? c0 : (nt == 1) ? c1 : (nt == 2) ? c2 : c3;
        const int n = n0 + nt * 16 + q16;
        if (n >= kN) continue;
#pragma unroll
        for (int r = 0; r < 4; ++r) {
            const int o = ob + 4 * u + r;
            const float val = A[r] + ((r == 0) ? bi0 : (r == 1) ? bi1
                                      : (r == 2) ? bi2 : bi3);
            float* yp = Y + (((size_t)b * kC + o) * kG) * kN + n;
            yp[0 * kN] = val;
            yp[1 * kN] = val;
            yp[2 * kN] = val;
            yp[3 * kN] = val;
        }
    }
}

extern "C" void kernel_launch(void* const* d_in, const int* in_sizes, int n_in,
                              void* d_out, int out_size, void* d_ws, size_t ws_size,
                              hipStream_t stream) {
    const float* x     = (const float*)d_in[0];
    // d_in[1]=h, d_in[2]=w (always 28; ignored)
    const float* dwq_w = (const float*)d_in[3];
    const float* bnq_g = (const float*)d_in[4];
    const float* bnq_b = (const float*)d_in[5];
    const float* bnq_m = (const float*)d_in[6];
    const float* bnq_v = (const float*)d_in[7];
    const float* pq_w  = (const float*)d_in[8];
    const float* pq_b  = (const float*)d_in[9];
    const float* dwk_w = (const float*)d_in[10];
    const float* bnk_g = (const float*)d_in[11];
    const float* bnk_b = (const float*)d_in[12];
    const float* bnk_m = (const float*)d_in[13];
    const float* bnk_v = (const float*)d_in[14];
    const float* pk_w  = (const float*)d_in[15];
    const float* pk_b  = (const float*)d_in[16];
    const float* dwv_w = (const float*)d_in[17];
    const float* bnv_g = (const float*)d_in[18];
    const float* bnv_b = (const float*)d_in[19];
    const float* bnv_m = (const float*)d_in[20];
    const float* bnv_v = (const float*)d_in[21];
    const float* pv_w  = (const float*)d_in[22];
    const float* pv_b  = (const float*)d_in[23];
    const float* po_w  = (const float*)d_in[24];
    const float* po_b  = (const float*)d_in[25];

    unsigned short* ws = (unsigned short*)d_ws;
    const size_t XSZ = (size_t)kB * kXP * kC;         // 1,277,952
    const size_t QSZ = (size_t)kB * kHEADS * kNP * 32; // 1,228,800
    unsigned short* Xq = ws;
    unsigned short* Xk = Xq + XSZ;
    unsigned short* Xv = Xk + XSZ;
    unsigned short* Qb = Xv + XSZ;
    unsigned short* Kb = Qb + QSZ;
    unsigned short* Vb = Kb + QSZ;
    unsigned short* AO = Vb + QSZ;
    unsigned short* Wq = AO + XSZ;
    unsigned short* Wk = Wq + kC * kC;
    unsigned short* Wv = Wk + kC * kC;
    unsigned short* Wo = Wv + kC * kC;

    prep_kernel<<<dim3(576), dim3(256), 0, stream>>>(
        pq_w, pk_w, pv_w, po_w, Wq, Wk, Wv, Wo);

    dwbn_kernel<<<dim3(kB * 98), dim3(192), 0, stream>>>(
        x,
        dwq_w, bnq_g, bnq_b, bnq_m, bnq_v,
        dwk_w, bnk_g, bnk_b, bnk_m, bnk_v,
        dwv_w, bnv_g, bnv_b, bnv_m, bnv_v,
        Xq, Xk, Xv);

    proj_kernel<<<dim3(13, 3, kB * 3), dim3(256), 0, stream>>>(
        Xq, Xk, Xv, Wq, Wk, Wv, pq_b, pk_b, pv_b, Qb, Kb, Vb);

    attn_kernel<<<dim3(kB * kHEADS * 49 / 4), dim3(256), 0, stream>>>(
        Qb, Kb, Vb, AO);

    outproj_kernel<<<dim3(13, 3, kB), dim3(256), 0, stream>>>(
        AO, Wo, po_b, (float*)d_out);
}